// Round 4
// baseline (329.012 us; speedup 1.0000x reference)
//
#include <hip/hip_runtime.h>

// GroupSort: x[32,256,64,64] fp32. For each channel pair (2k, 2k+1):
//   d = x[2k] - x[2k+1]; r = relu(d); out[2k] = x[2k] - r; out[2k+1] = x[2k+1] + r
// Pure streaming elementwise op: 128 MiB in + 128 MiB out, zero reuse.
//
// *** ROUND 4 = MEASUREMENT PROBE, NOT AN OPTIMIZATION ***
// The kernel is launched 3x (idempotent: x -> out each time). The dur_us
// delta vs the single-launch round (~228.5 us) equals ~2x the kernel's true
// dispatch time, which rocprof's top-5 can't show (saturated by 80 us
// harness fills). Revert to 1 launch next round.

typedef float f32x4 __attribute__((ext_vector_type(4)));

__device__ __forceinline__ f32x4 nt_load4(const f32x4* p) {
    return __builtin_nontemporal_load(p);
}
__device__ __forceinline__ void nt_store4(f32x4* p, f32x4 v) {
    __builtin_nontemporal_store(v, p);
}

__device__ __forceinline__ void pair_op(const f32x4 a, const f32x4 b,
                                        f32x4& lo, f32x4& hi) {
#pragma unroll
    for (int i = 0; i < 4; ++i) {
        float d = a[i] - b[i];
        float r = d > 0.0f ? d : 0.0f;
        lo[i] = a[i] - r;
        hi[i] = b[i] + r;
    }
}

__global__ __launch_bounds__(256) void groupsort_kernel(
    const f32x4* __restrict__ x, f32x4* __restrict__ out) {
    const long t = (long)blockIdx.x * blockDim.x + threadIdx.x;
    const long s = t * 2;                 // first float4 slot (of 2)
    const long pair   = s >> 10;          // channel-pair index (plane pair)
    const long within = s & 1023;
    const long even_off = pair * 2048 + within;
    const long odd_off  = even_off + 1024;

    const f32x4 a0 = nt_load4(x + even_off);
    const f32x4 a1 = nt_load4(x + even_off + 1);
    const f32x4 b0 = nt_load4(x + odd_off);
    const f32x4 b1 = nt_load4(x + odd_off + 1);

    f32x4 lo0, hi0, lo1, hi1;
    pair_op(a0, b0, lo0, hi0);
    pair_op(a1, b1, lo1, hi1);

    nt_store4(out + even_off,     lo0);
    nt_store4(out + even_off + 1, lo1);
    nt_store4(out + odd_off,      hi0);
    nt_store4(out + odd_off + 1,  hi1);
}

extern "C" void kernel_launch(void* const* d_in, const int* in_sizes, int n_in,
                              void* d_out, int out_size, void* d_ws, size_t ws_size,
                              hipStream_t stream) {
    const f32x4* x = (const f32x4*)d_in[0];
    f32x4* out = (f32x4*)d_out;
    const int threads = 256;
    const int blocks = 2097152 / threads; // 8192
    // PROBE: 3 identical launches; output unchanged, delta measures kernel T.
    groupsort_kernel<<<blocks, threads, 0, stream>>>(x, out);
    groupsort_kernel<<<blocks, threads, 0, stream>>>(x, out);
    groupsort_kernel<<<blocks, threads, 0, stream>>>(x, out);
}